// Round 1
// 516.788 us; speedup vs baseline: 1.1938x; 1.1938x over previous
//
#include <hip/hip_runtime.h>
#include <math.h>

// Round 9: attention kernel gets (a) XOR-swizzled Ks/Vs LDS layouts
// (pre-swizzled global source + swizzled ds_read, rule #21: dest of
// global_load_lds stays linear) and (b) double-buffered K/V staging with
// STAGE(t+1) issued before compute(t) — the T3 "minimum 2-phase" recipe.
// All other kernels unchanged from the 617 µs baseline.

#define D 2048
#define NH 16
#define DH 128
#define BB 2
#define LL 2048
#define BHD (BB*NH)      // 32
#define MROWS (BB*LL)    // 4096
#define KDIM D

typedef __attribute__((ext_vector_type(8))) short short8;
typedef __attribute__((ext_vector_type(4))) float floatx4;

// fp32 -> bf16, round-to-nearest-even
__device__ __forceinline__ unsigned short f2bf(float f) {
    unsigned u = __float_as_uint(f);
    unsigned r = u + 0x7FFFu + ((u >> 16) & 1u);
    return (unsigned short)(r >> 16);
}
__device__ __forceinline__ float bf2f(unsigned short u) {
    return __uint_as_float(((unsigned)u) << 16);
}

// async global->LDS DMA, 16 B/lane; LDS dest is wave-uniform base + lane*16
__device__ __forceinline__ void async16(const void* g, void* lds) {
    __builtin_amdgcn_global_load_lds(
        (const __attribute__((address_space(1))) unsigned int*)g,
        (__attribute__((address_space(3))) unsigned int*)lds, 16, 0, 0);
}

// ---------------------------------------------------------------------------
// elementwise fp32 -> bf16 cast, float4-vectorized
// ---------------------------------------------------------------------------
__global__ __launch_bounds__(256)
void cast_bf16_kernel_v2(const float* __restrict__ in,
                         unsigned short* __restrict__ out, int n4)
{
    int i = blockIdx.x * 256 + threadIdx.x;
    if (i < n4) {
        float4 v = ((const float4*)in)[i];
        ushort4 o;
        o.x = f2bf(v.x); o.y = f2bf(v.y); o.z = f2bf(v.z); o.w = f2bf(v.w);
        ((ushort4*)out)[i] = o;
    }
}

// ---------------------------------------------------------------------------
// W (K x N fp32 row-major) -> Wt (N x K bf16 row-major), 32x32 LDS tiles
// ---------------------------------------------------------------------------
__global__ __launch_bounds__(256)
void transpose_cast_kernel_v2(const float* __restrict__ W,
                              unsigned short* __restrict__ Wt, int K, int N)
{
    __shared__ float tile[32][33];
    const int tx = threadIdx.x & 31, ty = threadIdx.x >> 5;  // ty in 0..7
    const int n0 = blockIdx.x * 32, k0 = blockIdx.y * 32;
#pragma unroll
    for (int r = 0; r < 4; r++)
        tile[ty + 8 * r][tx] = W[(size_t)(k0 + ty + 8 * r) * N + n0 + tx];
    __syncthreads();
#pragma unroll
    for (int r = 0; r < 4; r++)
        Wt[(size_t)(n0 + ty + 8 * r) * K + k0 + tx] = f2bf(tile[tx][ty + 8 * r]);
}

// ---------------------------------------------------------------------------
// V (bh, l, dh) -> Vt (bh, dh, l), bf16, 32x32 LDS tiles (+2B pad row)
// ---------------------------------------------------------------------------
__global__ __launch_bounds__(256)
void transpose_v_kernel_v2(const unsigned short* __restrict__ Vb,
                           unsigned short* __restrict__ VtG)
{
    __shared__ unsigned short tile[32][34];
    const int tx = threadIdx.x & 31, ty = threadIdx.x >> 5;
    const int l0 = blockIdx.x * 32, d0 = blockIdx.y * 32;
    const int bh = blockIdx.z;
    const unsigned short* src = Vb + (size_t)bh * LL * DH;
    unsigned short* dst = VtG + (size_t)bh * DH * LL;
#pragma unroll
    for (int r = 0; r < 4; r++)
        tile[ty + 8 * r][tx] = src[(size_t)(l0 + ty + 8 * r) * DH + d0 + tx];
    __syncthreads();
#pragma unroll
    for (int r = 0; r < 4; r++)
        dst[(size_t)(d0 + ty + 8 * r) * LL + l0 + tx] = tile[tx][ty + 8 * r];
}

// ---------------------------------------------------------------------------
// bf16 MFMA GEMM, m97 structure: C(MxN) = A(MxK) * Bt(NxK)^T.
// 128x128 block tile, BK=32, 4 waves each owning a 64x64 quadrant.
// MODE 0: fp32 store to C. MODE 1: bf16 scatter to Q/K/V in (B,H,L,Dh).
// ---------------------------------------------------------------------------
template<int N, int MODE>
__global__ __launch_bounds__(256)
void mfma_gemm_v2(const unsigned short* __restrict__ A,
                  const unsigned short* __restrict__ Bt,
                  float* __restrict__ C, unsigned short* __restrict__ Qo,
                  unsigned short* __restrict__ Ko, unsigned short* __restrict__ Vo)
{
    __shared__ unsigned short As[128 * 32];   // [m][k] contiguous (DMA order)
    __shared__ unsigned short Bs[128 * 32];   // [n][k] contiguous
    const int t = threadIdx.x;
    const int w = t >> 6, lane = t & 63;
    const int lrow = lane & 15, quad = lane >> 4;
    const int m0 = blockIdx.y * 128, n0 = blockIdx.x * 128;
    const int wm = (w >> 1) * 64, wn = (w & 1) * 64;

    floatx4 acc[4][4];
#pragma unroll
    for (int i = 0; i < 4; i++)
#pragma unroll
        for (int j = 0; j < 4; j++) acc[i][j] = (floatx4){0.f, 0.f, 0.f, 0.f};

    const int srow = 32 * w + (lane >> 2);
    const int sseg = (lane & 3) * 8;

    for (int k0 = 0; k0 < KDIM; k0 += 32) {
        __syncthreads();
        async16(&A [(size_t)(m0 + srow)      * KDIM + k0 + sseg], &As[(32 * w)      * 32]);
        async16(&A [(size_t)(m0 + srow + 16) * KDIM + k0 + sseg], &As[(32 * w + 16) * 32]);
        async16(&Bt[(size_t)(n0 + srow)      * KDIM + k0 + sseg], &Bs[(32 * w)      * 32]);
        async16(&Bt[(size_t)(n0 + srow + 16) * KDIM + k0 + sseg], &Bs[(32 * w + 16) * 32]);
        __syncthreads();

        short8 a[4], b[4];
#pragma unroll
        for (int i = 0; i < 4; i++)
            a[i] = *(const short8*)&As[(wm + i * 16 + lrow) * 32 + quad * 8];
#pragma unroll
        for (int j = 0; j < 4; j++)
            b[j] = *(const short8*)&Bs[(wn + j * 16 + lrow) * 32 + quad * 8];
#pragma unroll
        for (int i = 0; i < 4; i++)
#pragma unroll
            for (int j = 0; j < 4; j++)
                acc[i][j] = __builtin_amdgcn_mfma_f32_16x16x32_bf16(a[i], b[j], acc[i][j], 0, 0, 0);
    }

    // C/D fragment layout: col = lane&15, row = quad*4 + reg (m89-verified)
    if (MODE == 0) {
#pragma unroll
        for (int i = 0; i < 4; i++)
#pragma unroll
            for (int j = 0; j < 4; j++) {
                int col = n0 + wn + j * 16 + lrow;
#pragma unroll
                for (int r = 0; r < 4; r++) {
                    int m = m0 + wm + i * 16 + quad * 4 + r;
                    C[(size_t)m * N + col] = acc[i][j][r];
                }
            }
    } else {
        const int s = n0 >> 11;              // qkv slot, uniform per block
        const int h = (n0 & 2047) >> 7;
        unsigned short* dst = (s == 0) ? Qo : (s == 1) ? Ko : Vo;
#pragma unroll
        for (int i = 0; i < 4; i++)
#pragma unroll
            for (int j = 0; j < 4; j++) {
                int dh = wn + j * 16 + lrow;
#pragma unroll
                for (int r = 0; r < 4; r++) {
                    int m = m0 + wm + i * 16 + quad * 4 + r;
                    int b = m >> 11, l = m & 2047;
                    dst[(((size_t)b * NH + h) * LL + l) * DH + dh] = f2bf(acc[i][j][r]);
                }
            }
    }
}

// ---------------------------------------------------------------------------
// RoPE + L2-normalize, in place on bf16 Q/K (fp32 internal); Q *= s_qk.
// One 128-thread block per (bh, l).
// ---------------------------------------------------------------------------
__global__ __launch_bounds__(128)
void rope_norm_kernel_v2(unsigned short* __restrict__ Q,
                         unsigned short* __restrict__ K,
                         const float* __restrict__ s_qk_ptr)
{
    const int l  = blockIdx.x;
    const int bh = blockIdx.y;
    const int d  = threadIdx.x;
    __shared__ float sh[128];

    const size_t base = ((size_t)bh * LL + l) * DH + d;
    float qv = bf2f(Q[base]);
    float kv = bf2f(K[base]);

    const int i = d & 63;
    // inv_freq = 10000^(-i/64); ln(10000)/64 = 0.14391156831
    float ang = (float)l * expf(-0.14391157f * (float)i);
    float c = cosf(ang), s = sinf(ang);

    sh[d] = qv; __syncthreads();
    float qrot = (d < 64) ? -sh[d + 64] : sh[d - 64];
    float qr = fmaf(qv, c, qrot * s);
    __syncthreads();

    sh[d] = kv; __syncthreads();
    float krot = (d < 64) ? -sh[d + 64] : sh[d - 64];
    float kr = fmaf(kv, c, krot * s);
    __syncthreads();

    sh[d] = qr * qr; __syncthreads();
    for (int st = 64; st > 0; st >>= 1) {
        if (d < st) sh[d] += sh[d + st];
        __syncthreads();
    }
    float qn = sqrtf(sh[0]);
    __syncthreads();

    sh[d] = kr * kr; __syncthreads();
    for (int st = 64; st > 0; st >>= 1) {
        if (d < st) sh[d] += sh[d + st];
        __syncthreads();
    }
    float kn = sqrtf(sh[0]);

    float sqk = s_qk_ptr[0];
    Q[base] = f2bf(qr / fmaxf(qn, 1e-12f) * sqk);
    K[base] = f2bf(kr / fmaxf(kn, 1e-12f));
}

// ---------------------------------------------------------------------------
// bf16 MFMA flash attention, causal. BQ=64 (4 waves x 16 rows), BK=64.
// Round 9 changes vs v2:
//   * Ks/Vs double-buffered; STAGE(t+1) issued before compute(t); single
//     __syncthreads() per tile (its vmcnt(0)+lgkmcnt(0) drain is the only
//     wait) — loads fly across the whole compute phase.
//   * Ks/Vs XOR-swizzled (slot ^= row&7, 16B slots): global source column
//     is inverse-permuted per-lane (LDS dest of global_load_lds must stay
//     linear), ds_read applies the same involution. Kills the 16-way bank
//     conflict (256B/128B row strides -> bank group depended only on quad).
// ---------------------------------------------------------------------------
#define ABQ 64
#define ABK 64
__global__ __launch_bounds__(256)
void attn_mfma_kernel_v3(const unsigned short* __restrict__ Q,
                         const unsigned short* __restrict__ K,
                         const unsigned short* __restrict__ Vt,
                         unsigned short* __restrict__ AOb)
{
    __shared__ __align__(16) unsigned short Ks[2][ABK * DH];   // 2 x 16 KB
    __shared__ __align__(16) unsigned short Vs[2][DH * ABK];   // 2 x 16 KB
    __shared__ __align__(16) unsigned short Ps[4][16][72];     // ~9 KB padded

    const int t = threadIdx.x;
    const int w = t >> 6, lane = t & 63;
    const int lrow = lane & 15, quad = lane >> 4;
    const int bh = blockIdx.y;
    const int qt = gridDim.x - 1 - blockIdx.x;   // heavy q-tiles first
    const int q0 = qt * ABQ;
    const int qw = q0 + w * 16;                  // wave's first q-row

    const unsigned short* Qb = Q  + (size_t)bh * LL * DH;
    const unsigned short* Kb = K  + (size_t)bh * LL * DH;
    const unsigned short* Vg = Vt + (size_t)bh * DH * LL;

    // Q A-fragments: row = lrow, k = kk*32 + quad*8 + j
    short8 aq[4];
#pragma unroll
    for (int kk = 0; kk < 4; kk++)
        aq[kk] = *(const short8*)&Qb[(size_t)(qw + lrow) * DH + kk * 32 + quad * 8];

    floatx4 oacc[8];
#pragma unroll
    for (int dt = 0; dt < 8; dt++) oacc[dt] = (floatx4){0.f, 0.f, 0.f, 0.f};
    float mrow[4] = {-1e30f, -1e30f, -1e30f, -1e30f};
    float lsum[4] = {0.f, 0.f, 0.f, 0.f};

    // stage one K/V tile into buffer `buf`; LDS dest linear, global source
    // column slot inverse-swizzled so that swizzled reads see row-major data
    auto STAGE = [&](int tile, int buf) {
        const int k0s = tile * ABK;
        // K tile: wave w stages key-rows 16w..16w+15 (256 B rows, 4 rows/call)
#pragma unroll
        for (int c = 0; c < 4; c++) {
            int row = 16 * w + 4 * c;
            int r   = row + (lane >> 4);                 // physical row
            int col = (lane & 15) ^ (r & 7);             // 16B-slot in row
            async16(&Kb[(size_t)(k0s + r) * DH + col * 8], &Ks[buf][row * DH]);
        }
        // V^T tile: wave w stages d-rows 32w..32w+31 (128 B rows, 8 rows/call)
#pragma unroll
        for (int c = 0; c < 4; c++) {
            int row = 32 * w + 8 * c;
            int r   = row + (lane >> 3);
            int col = (lane & 7) ^ (r & 7);
            async16(&Vg[(size_t)r * LL + k0s + col * 8], &Vs[buf][row * ABK]);
        }
    };

    const int ntiles = qt + 1;
    STAGE(0, 0);
    __syncthreads();       // compiler-emitted vmcnt(0) drain + barrier

    int cur = 0;
    for (int tile = 0; tile < ntiles; tile++) {
        const int k0 = tile * ABK;
        // prefetch next tile into the other buffer; its loads stay in flight
        // across this tile's compute and are drained by the end barrier
        if (tile + 1 < ntiles) STAGE(tile + 1, cur ^ 1);

        // S = Q K^T; sacc[j] holds keys j*16..j*16+15 for rows qw+quad*4+r
        floatx4 sacc[4];
#pragma unroll
        for (int j = 0; j < 4; j++) sacc[j] = (floatx4){0.f, 0.f, 0.f, 0.f};
#pragma unroll
        for (int kk = 0; kk < 4; kk++) {
#pragma unroll
            for (int j = 0; j < 4; j++) {
                int slot = (kk * 4 + quad) ^ (lrow & 7);   // swizzled 16B slot
                short8 bk = *(const short8*)&Ks[cur][(j * 16 + lrow) * DH + slot * 8];
                sacc[j] = __builtin_amdgcn_mfma_f32_16x16x32_bf16(aq[kk], bk, sacc[j], 0, 0, 0);
            }
        }

        // causal mask: fires only on the diagonal tile (vs wave's MIN q-row)
        if (k0 + ABK - 1 > qw) {
#pragma unroll
            for (int j = 0; j < 4; j++) {
                int key = k0 + j * 16 + lrow;
#pragma unroll
                for (int r = 0; r < 4; r++) {
                    int q = qw + quad * 4 + r;
                    if (key > q) sacc[j][r] = -1e30f;
                }
            }
        }

        // online softmax; each row's 16 scores live across a 16-lane group
        float alpha[4];
#pragma unroll
        for (int r = 0; r < 4; r++) {
            float mt = fmaxf(fmaxf(sacc[0][r], sacc[1][r]),
                             fmaxf(sacc[2][r], sacc[3][r]));
#pragma unroll
            for (int off = 1; off < 16; off <<= 1)
                mt = fmaxf(mt, __shfl_xor(mt, off, 16));
            float mn = fmaxf(mrow[r], mt);
            alpha[r] = __expf(mrow[r] - mn);
            mrow[r] = mn;
        }
        // P = exp(S - m): stage bf16 into per-wave LDS; reduce row sums
#pragma unroll
        for (int r = 0; r < 4; r++) {
            float rs = 0.f;
#pragma unroll
            for (int j = 0; j < 4; j++) {
                float p = __expf(sacc[j][r] - mrow[r]);
                rs += p;
                Ps[w][quad * 4 + r][j * 16 + lrow] = f2bf(p);
            }
#pragma unroll
            for (int off = 1; off < 16; off <<= 1)
                rs += __shfl_xor(rs, off, 16);
            lsum[r] = lsum[r] * alpha[r] + rs;
        }

        // O = O*alpha + P @ V
#pragma unroll
        for (int dt = 0; dt < 8; dt++)
#pragma unroll
            for (int r = 0; r < 4; r++) oacc[dt][r] *= alpha[r];
#pragma unroll
        for (int kk2 = 0; kk2 < 2; kk2++) {
            short8 pa = *(const short8*)&Ps[w][lrow][kk2 * 32 + quad * 8];
#pragma unroll
            for (int dt = 0; dt < 8; dt++) {
                int slot = (kk2 * 4 + quad) ^ (lrow & 7);  // swizzled 16B slot
                short8 bv = *(const short8*)&Vs[cur][(dt * 16 + lrow) * ABK + slot * 8];
                oacc[dt] = __builtin_amdgcn_mfma_f32_16x16x32_bf16(pa, bv, oacc[dt], 0, 0, 0);
            }
        }

        __syncthreads();   // drains prefetch vmcnt + guards buffer reuse
        cur ^= 1;
    }

    // epilogue: divide by row sum, store bf16 to (B, L, D)
    const int b = bh >> 4, h = bh & 15;
#pragma unroll
    for (int r = 0; r < 4; r++) {
        float inv = 1.f / lsum[r];
        int q = qw + quad * 4 + r;
        size_t base = ((size_t)b * LL + q) * D + h * DH;
#pragma unroll
        for (int dt = 0; dt < 8; dt++)
            AOb[base + dt * 16 + lrow] = f2bf(oacc[dt][r] * inv);
    }
}

// ---------------------------------------------------------------------------
extern "C" void kernel_launch(void* const* d_in, const int* in_sizes, int n_in,
                              void* d_out, int out_size, void* d_ws, size_t ws_size,
                              hipStream_t stream)
{
    const float* x     = (const float*)d_in[0];
    const float* w_qkv = (const float*)d_in[1];
    const float* w_out = (const float*)d_in[2];
    const float* s_qk  = (const float*)d_in[3];
    float* out = (float*)d_out;

    const size_t SZ = (size_t)BB * NH * LL * DH;   // 8388608 elements
    unsigned short* u = (unsigned short*)d_ws;
    unsigned short* xb    = u;                               // x bf16 -> later AO bf16
    unsigned short* wqkvT = xb    + (size_t)MROWS * KDIM;    // 6144 x 2048
    unsigned short* woutT = wqkvT + (size_t)(3 * D) * KDIM;  // 2048 x 2048
    unsigned short* Qb    = woutT + (size_t)D * KDIM;
    unsigned short* Kb    = Qb + SZ;
    unsigned short* Vb    = Kb + SZ;
    unsigned short* VtG   = Vb + SZ;

    // 1) x -> bf16
    cast_bf16_kernel_v2<<<(MROWS * KDIM / 4 + 255) / 256, 256, 0, stream>>>(
        x, xb, MROWS * KDIM / 4);
    // 2) w_qkv -> (3D x K) bf16
    transpose_cast_kernel_v2<<<dim3(3 * D / 32, KDIM / 32), 256, 0, stream>>>(
        w_qkv, wqkvT, KDIM, 3 * D);
    // 3) QKV projection, bf16 scatter into (B,H,L,Dh)
    mfma_gemm_v2<3 * D, 1><<<dim3(3 * D / 128, MROWS / 128), 256, 0, stream>>>(
        xb, wqkvT, nullptr, Qb, Kb, Vb);
    // 4) RoPE + normalize in place (+ s_qk into Q)
    rope_norm_kernel_v2<<<dim3(LL, BHD), 128, 0, stream>>>(Qb, Kb, s_qk);
    // 5) V -> V^T (bh, dh, l)
    transpose_v_kernel_v2<<<dim3(LL / 32, DH / 32, BHD), 256, 0, stream>>>(Vb, VtG);
    // 6) flash attention -> AO bf16 (B,L,D), reusing xb
    attn_mfma_kernel_v3<<<dim3(LL / ABQ, BHD), 256, 0, stream>>>(Qb, Kb, VtG, xb);
    // 7) w_out -> bf16
    transpose_cast_kernel_v2<<<dim3(D / 32, D / 32), 256, 0, stream>>>(
        w_out, woutT, D, D);
    // 8) output projection
    mfma_gemm_v2<D, 0><<<dim3(D / 128, MROWS / 128), 256, 0, stream>>>(
        xb, woutT, out, nullptr, nullptr, nullptr);
}

// Round 2
// 503.408 us; speedup vs baseline: 1.2255x; 1.0266x over previous
//
#include <hip/hip_runtime.h>
#include <math.h>

// Round 10: attention softmax cross-lane reductions moved from
// __shfl_xor/ds_bpermute (LDS pipe, ~100cy latency each, 32 per tile in
// serial chains) to DPP-modified VALU ops (quad_perm xor1/xor2 butterflies +
// row_ror:4/8 rotation-reduce, exact for max and sum within 16-lane groups).
// Plus T5 s_setprio(1) around both MFMA clusters. All other kernels and the
// round-9 dbuf+swizzle attn structure unchanged.

#define D 2048
#define NH 16
#define DH 128
#define BB 2
#define LL 2048
#define BHD (BB*NH)      // 32
#define MROWS (BB*LL)    // 4096
#define KDIM D

typedef __attribute__((ext_vector_type(8))) short short8;
typedef __attribute__((ext_vector_type(4))) float floatx4;

// fp32 -> bf16, round-to-nearest-even
__device__ __forceinline__ unsigned short f2bf(float f) {
    unsigned u = __float_as_uint(f);
    unsigned r = u + 0x7FFFu + ((u >> 16) & 1u);
    return (unsigned short)(r >> 16);
}
__device__ __forceinline__ float bf2f(unsigned short u) {
    return __uint_as_float(((unsigned)u) << 16);
}

// async global->LDS DMA, 16 B/lane; LDS dest is wave-uniform base + lane*16
__device__ __forceinline__ void async16(const void* g, void* lds) {
    __builtin_amdgcn_global_load_lds(
        (const __attribute__((address_space(1))) unsigned int*)g,
        (__attribute__((address_space(3))) unsigned int*)lds, 16, 0, 0);
}

// DPP lane-move within 16-lane rows (VALU-speed, no LDS pipe).
// ctrl: 0xB1 = quad_perm xor1, 0x4E = quad_perm xor2,
//       0x124 = row_ror:4, 0x128 = row_ror:8
template<int CTRL>
__device__ __forceinline__ float dpp_movf(float x) {
    return __int_as_float(__builtin_amdgcn_update_dpp(
        0, __float_as_int(x), CTRL, 0xF, 0xF, true));
}
// full 16-lane max: quad butterflies then rotation-reduce (exact, all lanes)
__device__ __forceinline__ float row_max16(float x) {
    x = fmaxf(x, dpp_movf<0xB1>(x));
    x = fmaxf(x, dpp_movf<0x4E>(x));
    x = fmaxf(x, dpp_movf<0x124>(x));
    x = fmaxf(x, dpp_movf<0x128>(x));
    return x;
}
// full 16-lane sum: after quad butterflies each quad holds its subtotal;
// ror4 adds quad+1, ror8 adds quads +2,+3 -> every lane has the total
__device__ __forceinline__ float row_sum16(float x) {
    x += dpp_movf<0xB1>(x);
    x += dpp_movf<0x4E>(x);
    x += dpp_movf<0x124>(x);
    x += dpp_movf<0x128>(x);
    return x;
}

// ---------------------------------------------------------------------------
// elementwise fp32 -> bf16 cast, float4-vectorized
// ---------------------------------------------------------------------------
__global__ __launch_bounds__(256)
void cast_bf16_kernel_v2(const float* __restrict__ in,
                         unsigned short* __restrict__ out, int n4)
{
    int i = blockIdx.x * 256 + threadIdx.x;
    if (i < n4) {
        float4 v = ((const float4*)in)[i];
        ushort4 o;
        o.x = f2bf(v.x); o.y = f2bf(v.y); o.z = f2bf(v.z); o.w = f2bf(v.w);
        ((ushort4*)out)[i] = o;
    }
}

// ---------------------------------------------------------------------------
// W (K x N fp32 row-major) -> Wt (N x K bf16 row-major), 32x32 LDS tiles
// ---------------------------------------------------------------------------
__global__ __launch_bounds__(256)
void transpose_cast_kernel_v2(const float* __restrict__ W,
                              unsigned short* __restrict__ Wt, int K, int N)
{
    __shared__ float tile[32][33];
    const int tx = threadIdx.x & 31, ty = threadIdx.x >> 5;  // ty in 0..7
    const int n0 = blockIdx.x * 32, k0 = blockIdx.y * 32;
#pragma unroll
    for (int r = 0; r < 4; r++)
        tile[ty + 8 * r][tx] = W[(size_t)(k0 + ty + 8 * r) * N + n0 + tx];
    __syncthreads();
#pragma unroll
    for (int r = 0; r < 4; r++)
        Wt[(size_t)(n0 + ty + 8 * r) * K + k0 + tx] = f2bf(tile[tx][ty + 8 * r]);
}

// ---------------------------------------------------------------------------
// V (bh, l, dh) -> Vt (bh, dh, l), bf16, 32x32 LDS tiles (+2B pad row)
// ---------------------------------------------------------------------------
__global__ __launch_bounds__(256)
void transpose_v_kernel_v2(const unsigned short* __restrict__ Vb,
                           unsigned short* __restrict__ VtG)
{
    __shared__ unsigned short tile[32][34];
    const int tx = threadIdx.x & 31, ty = threadIdx.x >> 5;
    const int l0 = blockIdx.x * 32, d0 = blockIdx.y * 32;
    const int bh = blockIdx.z;
    const unsigned short* src = Vb + (size_t)bh * LL * DH;
    unsigned short* dst = VtG + (size_t)bh * DH * LL;
#pragma unroll
    for (int r = 0; r < 4; r++)
        tile[ty + 8 * r][tx] = src[(size_t)(l0 + ty + 8 * r) * DH + d0 + tx];
    __syncthreads();
#pragma unroll
    for (int r = 0; r < 4; r++)
        dst[(size_t)(d0 + ty + 8 * r) * LL + l0 + tx] = tile[tx][ty + 8 * r];
}

// ---------------------------------------------------------------------------
// bf16 MFMA GEMM, m97 structure: C(MxN) = A(MxK) * Bt(NxK)^T.
// 128x128 block tile, BK=32, 4 waves each owning a 64x64 quadrant.
// MODE 0: fp32 store to C. MODE 1: bf16 scatter to Q/K/V in (B,H,L,Dh).
// ---------------------------------------------------------------------------
template<int N, int MODE>
__global__ __launch_bounds__(256)
void mfma_gemm_v2(const unsigned short* __restrict__ A,
                  const unsigned short* __restrict__ Bt,
                  float* __restrict__ C, unsigned short* __restrict__ Qo,
                  unsigned short* __restrict__ Ko, unsigned short* __restrict__ Vo)
{
    __shared__ unsigned short As[128 * 32];   // [m][k] contiguous (DMA order)
    __shared__ unsigned short Bs[128 * 32];   // [n][k] contiguous
    const int t = threadIdx.x;
    const int w = t >> 6, lane = t & 63;
    const int lrow = lane & 15, quad = lane >> 4;
    const int m0 = blockIdx.y * 128, n0 = blockIdx.x * 128;
    const int wm = (w >> 1) * 64, wn = (w & 1) * 64;

    floatx4 acc[4][4];
#pragma unroll
    for (int i = 0; i < 4; i++)
#pragma unroll
        for (int j = 0; j < 4; j++) acc[i][j] = (floatx4){0.f, 0.f, 0.f, 0.f};

    const int srow = 32 * w + (lane >> 2);
    const int sseg = (lane & 3) * 8;

    for (int k0 = 0; k0 < KDIM; k0 += 32) {
        __syncthreads();
        async16(&A [(size_t)(m0 + srow)      * KDIM + k0 + sseg], &As[(32 * w)      * 32]);
        async16(&A [(size_t)(m0 + srow + 16) * KDIM + k0 + sseg], &As[(32 * w + 16) * 32]);
        async16(&Bt[(size_t)(n0 + srow)      * KDIM + k0 + sseg], &Bs[(32 * w)      * 32]);
        async16(&Bt[(size_t)(n0 + srow + 16) * KDIM + k0 + sseg], &Bs[(32 * w + 16) * 32]);
        __syncthreads();

        short8 a[4], b[4];
#pragma unroll
        for (int i = 0; i < 4; i++)
            a[i] = *(const short8*)&As[(wm + i * 16 + lrow) * 32 + quad * 8];
#pragma unroll
        for (int j = 0; j < 4; j++)
            b[j] = *(const short8*)&Bs[(wn + j * 16 + lrow) * 32 + quad * 8];
#pragma unroll
        for (int i = 0; i < 4; i++)
#pragma unroll
            for (int j = 0; j < 4; j++)
                acc[i][j] = __builtin_amdgcn_mfma_f32_16x16x32_bf16(a[i], b[j], acc[i][j], 0, 0, 0);
    }

    // C/D fragment layout: col = lane&15, row = quad*4 + reg (m89-verified)
    if (MODE == 0) {
#pragma unroll
        for (int i = 0; i < 4; i++)
#pragma unroll
            for (int j = 0; j < 4; j++) {
                int col = n0 + wn + j * 16 + lrow;
#pragma unroll
                for (int r = 0; r < 4; r++) {
                    int m = m0 + wm + i * 16 + quad * 4 + r;
                    C[(size_t)m * N + col] = acc[i][j][r];
                }
            }
    } else {
        const int s = n0 >> 11;              // qkv slot, uniform per block
        const int h = (n0 & 2047) >> 7;
        unsigned short* dst = (s == 0) ? Qo : (s == 1) ? Ko : Vo;
#pragma unroll
        for (int i = 0; i < 4; i++)
#pragma unroll
            for (int j = 0; j < 4; j++) {
                int dh = wn + j * 16 + lrow;
#pragma unroll
                for (int r = 0; r < 4; r++) {
                    int m = m0 + wm + i * 16 + quad * 4 + r;
                    int b = m >> 11, l = m & 2047;
                    dst[(((size_t)b * NH + h) * LL + l) * DH + dh] = f2bf(acc[i][j][r]);
                }
            }
    }
}

// ---------------------------------------------------------------------------
// RoPE + L2-normalize, in place on bf16 Q/K (fp32 internal); Q *= s_qk.
// One 128-thread block per (bh, l).
// ---------------------------------------------------------------------------
__global__ __launch_bounds__(128)
void rope_norm_kernel_v2(unsigned short* __restrict__ Q,
                         unsigned short* __restrict__ K,
                         const float* __restrict__ s_qk_ptr)
{
    const int l  = blockIdx.x;
    const int bh = blockIdx.y;
    const int d  = threadIdx.x;
    __shared__ float sh[128];

    const size_t base = ((size_t)bh * LL + l) * DH + d;
    float qv = bf2f(Q[base]);
    float kv = bf2f(K[base]);

    const int i = d & 63;
    // inv_freq = 10000^(-i/64); ln(10000)/64 = 0.14391156831
    float ang = (float)l * expf(-0.14391157f * (float)i);
    float c = cosf(ang), s = sinf(ang);

    sh[d] = qv; __syncthreads();
    float qrot = (d < 64) ? -sh[d + 64] : sh[d - 64];
    float qr = fmaf(qv, c, qrot * s);
    __syncthreads();

    sh[d] = kv; __syncthreads();
    float krot = (d < 64) ? -sh[d + 64] : sh[d - 64];
    float kr = fmaf(kv, c, krot * s);
    __syncthreads();

    sh[d] = qr * qr; __syncthreads();
    for (int st = 64; st > 0; st >>= 1) {
        if (d < st) sh[d] += sh[d + st];
        __syncthreads();
    }
    float qn = sqrtf(sh[0]);
    __syncthreads();

    sh[d] = kr * kr; __syncthreads();
    for (int st = 64; st > 0; st >>= 1) {
        if (d < st) sh[d] += sh[d + st];
        __syncthreads();
    }
    float kn = sqrtf(sh[0]);

    float sqk = s_qk_ptr[0];
    Q[base] = f2bf(qr / fmaxf(qn, 1e-12f) * sqk);
    K[base] = f2bf(kr / fmaxf(kn, 1e-12f));
}

// ---------------------------------------------------------------------------
// bf16 MFMA flash attention, causal. BQ=64 (4 waves x 16 rows), BK=64.
// Round 10 changes vs v3:
//   * softmax 16-lane reductions via DPP (quad_perm xor1/xor2 + row_ror:4/8)
//     instead of __shfl_xor/ds_bpermute — removes ~32 LDS-latency ops per
//     tile from the critical path at ~1 wave/SIMD occupancy.
//   * s_setprio(1) around the QK^T and PV MFMA clusters (T5).
// ---------------------------------------------------------------------------
#define ABQ 64
#define ABK 64
__global__ __launch_bounds__(256)
void attn_mfma_kernel_v4(const unsigned short* __restrict__ Q,
                         const unsigned short* __restrict__ K,
                         const unsigned short* __restrict__ Vt,
                         unsigned short* __restrict__ AOb)
{
    __shared__ __align__(16) unsigned short Ks[2][ABK * DH];   // 2 x 16 KB
    __shared__ __align__(16) unsigned short Vs[2][DH * ABK];   // 2 x 16 KB
    __shared__ __align__(16) unsigned short Ps[4][16][72];     // ~9 KB padded

    const int t = threadIdx.x;
    const int w = t >> 6, lane = t & 63;
    const int lrow = lane & 15, quad = lane >> 4;
    const int bh = blockIdx.y;
    const int qt = gridDim.x - 1 - blockIdx.x;   // heavy q-tiles first
    const int q0 = qt * ABQ;
    const int qw = q0 + w * 16;                  // wave's first q-row

    const unsigned short* Qb = Q  + (size_t)bh * LL * DH;
    const unsigned short* Kb = K  + (size_t)bh * LL * DH;
    const unsigned short* Vg = Vt + (size_t)bh * DH * LL;

    // Q A-fragments: row = lrow, k = kk*32 + quad*8 + j
    short8 aq[4];
#pragma unroll
    for (int kk = 0; kk < 4; kk++)
        aq[kk] = *(const short8*)&Qb[(size_t)(qw + lrow) * DH + kk * 32 + quad * 8];

    floatx4 oacc[8];
#pragma unroll
    for (int dt = 0; dt < 8; dt++) oacc[dt] = (floatx4){0.f, 0.f, 0.f, 0.f};
    float mrow[4] = {-1e30f, -1e30f, -1e30f, -1e30f};
    float lsum[4] = {0.f, 0.f, 0.f, 0.f};

    // stage one K/V tile into buffer `buf`; LDS dest linear, global source
    // column slot inverse-swizzled so that swizzled reads see row-major data
    auto STAGE = [&](int tile, int buf) {
        const int k0s = tile * ABK;
        // K tile: wave w stages key-rows 16w..16w+15 (256 B rows, 4 rows/call)
#pragma unroll
        for (int c = 0; c < 4; c++) {
            int row = 16 * w + 4 * c;
            int r   = row + (lane >> 4);                 // physical row
            int col = (lane & 15) ^ (r & 7);             // 16B-slot in row
            async16(&Kb[(size_t)(k0s + r) * DH + col * 8], &Ks[buf][row * DH]);
        }
        // V^T tile: wave w stages d-rows 32w..32w+31 (128 B rows, 8 rows/call)
#pragma unroll
        for (int c = 0; c < 4; c++) {
            int row = 32 * w + 8 * c;
            int r   = row + (lane >> 3);
            int col = (lane & 7) ^ (r & 7);
            async16(&Vg[(size_t)r * LL + k0s + col * 8], &Vs[buf][row * ABK]);
        }
    };

    const int ntiles = qt + 1;
    STAGE(0, 0);
    __syncthreads();       // compiler-emitted vmcnt(0) drain + barrier

    int cur = 0;
    for (int tile = 0; tile < ntiles; tile++) {
        const int k0 = tile * ABK;
        // prefetch next tile into the other buffer; its loads stay in flight
        // across this tile's compute and are drained by the end barrier
        if (tile + 1 < ntiles) STAGE(tile + 1, cur ^ 1);

        // S = Q K^T; sacc[j] holds keys j*16..j*16+15 for rows qw+quad*4+r
        floatx4 sacc[4];
#pragma unroll
        for (int j = 0; j < 4; j++) sacc[j] = (floatx4){0.f, 0.f, 0.f, 0.f};
        __builtin_amdgcn_s_setprio(1);
#pragma unroll
        for (int kk = 0; kk < 4; kk++) {
#pragma unroll
            for (int j = 0; j < 4; j++) {
                int slot = (kk * 4 + quad) ^ (lrow & 7);   // swizzled 16B slot
                short8 bk = *(const short8*)&Ks[cur][(j * 16 + lrow) * DH + slot * 8];
                sacc[j] = __builtin_amdgcn_mfma_f32_16x16x32_bf16(aq[kk], bk, sacc[j], 0, 0, 0);
            }
        }
        __builtin_amdgcn_s_setprio(0);

        // causal mask: fires only on the diagonal tile (vs wave's MIN q-row)
        if (k0 + ABK - 1 > qw) {
#pragma unroll
            for (int j = 0; j < 4; j++) {
                int key = k0 + j * 16 + lrow;
#pragma unroll
                for (int r = 0; r < 4; r++) {
                    int q = qw + quad * 4 + r;
                    if (key > q) sacc[j][r] = -1e30f;
                }
            }
        }

        // online softmax; each row's 16 scores live across a 16-lane group.
        // All cross-lane reduction via DPP (VALU pipe, no ds_bpermute).
        float alpha[4];
#pragma unroll
        for (int r = 0; r < 4; r++) {
            float mt = fmaxf(fmaxf(sacc[0][r], sacc[1][r]),
                             fmaxf(sacc[2][r], sacc[3][r]));
            mt = row_max16(mt);
            float mn = fmaxf(mrow[r], mt);
            alpha[r] = __expf(mrow[r] - mn);
            mrow[r] = mn;
        }
        // P = exp(S - m): stage bf16 into per-wave LDS; reduce row sums
#pragma unroll
        for (int r = 0; r < 4; r++) {
            float rs = 0.f;
#pragma unroll
            for (int j = 0; j < 4; j++) {
                float p = __expf(sacc[j][r] - mrow[r]);
                rs += p;
                Ps[w][quad * 4 + r][j * 16 + lrow] = f2bf(p);
            }
            rs = row_sum16(rs);
            lsum[r] = lsum[r] * alpha[r] + rs;
        }

        // O = O*alpha + P @ V
#pragma unroll
        for (int dt = 0; dt < 8; dt++)
#pragma unroll
            for (int r = 0; r < 4; r++) oacc[dt][r] *= alpha[r];
        __builtin_amdgcn_s_setprio(1);
#pragma unroll
        for (int kk2 = 0; kk2 < 2; kk2++) {
            short8 pa = *(const short8*)&Ps[w][lrow][kk2 * 32 + quad * 8];
#pragma unroll
            for (int dt = 0; dt < 8; dt++) {
                int slot = (kk2 * 4 + quad) ^ (lrow & 7);  // swizzled 16B slot
                short8 bv = *(const short8*)&Vs[cur][(dt * 16 + lrow) * ABK + slot * 8];
                oacc[dt] = __builtin_amdgcn_mfma_f32_16x16x32_bf16(pa, bv, oacc[dt], 0, 0, 0);
            }
        }
        __builtin_amdgcn_s_setprio(0);

        __syncthreads();   // drains prefetch vmcnt + guards buffer reuse
        cur ^= 1;
    }

    // epilogue: divide by row sum, store bf16 to (B, L, D)
    const int b = bh >> 4, h = bh & 15;
#pragma unroll
    for (int r = 0; r < 4; r++) {
        float inv = 1.f / lsum[r];
        int q = qw + quad * 4 + r;
        size_t base = ((size_t)b * LL + q) * D + h * DH;
#pragma unroll
        for (int dt = 0; dt < 8; dt++)
            AOb[base + dt * 16 + lrow] = f2bf(oacc[dt][r] * inv);
    }
}

// ---------------------------------------------------------------------------
extern "C" void kernel_launch(void* const* d_in, const int* in_sizes, int n_in,
                              void* d_out, int out_size, void* d_ws, size_t ws_size,
                              hipStream_t stream)
{
    const float* x     = (const float*)d_in[0];
    const float* w_qkv = (const float*)d_in[1];
    const float* w_out = (const float*)d_in[2];
    const float* s_qk  = (const float*)d_in[3];
    float* out = (float*)d_out;

    const size_t SZ = (size_t)BB * NH * LL * DH;   // 8388608 elements
    unsigned short* u = (unsigned short*)d_ws;
    unsigned short* xb    = u;                               // x bf16 -> later AO bf16
    unsigned short* wqkvT = xb    + (size_t)MROWS * KDIM;    // 6144 x 2048
    unsigned short* woutT = wqkvT + (size_t)(3 * D) * KDIM;  // 2048 x 2048
    unsigned short* Qb    = woutT + (size_t)D * KDIM;
    unsigned short* Kb    = Qb + SZ;
    unsigned short* Vb    = Kb + SZ;
    unsigned short* VtG   = Vb + SZ;

    // 1) x -> bf16
    cast_bf16_kernel_v2<<<(MROWS * KDIM / 4 + 255) / 256, 256, 0, stream>>>(
        x, xb, MROWS * KDIM / 4);
    // 2) w_qkv -> (3D x K) bf16
    transpose_cast_kernel_v2<<<dim3(3 * D / 32, KDIM / 32), 256, 0, stream>>>(
        w_qkv, wqkvT, KDIM, 3 * D);
    // 3) QKV projection, bf16 scatter into (B,H,L,Dh)
    mfma_gemm_v2<3 * D, 1><<<dim3(3 * D / 128, MROWS / 128), 256, 0, stream>>>(
        xb, wqkvT, nullptr, Qb, Kb, Vb);
    // 4) RoPE + normalize in place (+ s_qk into Q)
    rope_norm_kernel_v2<<<dim3(LL, BHD), 128, 0, stream>>>(Qb, Kb, s_qk);
    // 5) V -> V^T (bh, dh, l)
    transpose_v_kernel_v2<<<dim3(LL / 32, DH / 32, BHD), 256, 0, stream>>>(Vb, VtG);
    // 6) flash attention -> AO bf16 (B,L,D), reusing xb
    attn_mfma_kernel_v4<<<dim3(LL / ABQ, BHD), 256, 0, stream>>>(Qb, Kb, VtG, xb);
    // 7) w_out -> bf16
    transpose_cast_kernel_v2<<<dim3(D / 32, D / 32), 256, 0, stream>>>(
        w_out, woutT, D, D);
    // 8) output projection
    mfma_gemm_v2<D, 0><<<dim3(D / 128, MROWS / 128), 256, 0, stream>>>(
        xb, woutT, out, nullptr, nullptr, nullptr);
}

// Round 3
// 438.505 us; speedup vs baseline: 1.4069x; 1.1480x over previous
//
#include <hip/hip_runtime.h>
#include <math.h>

// Round 11: attention reworked for LDS-bandwidth (the diagnosed bottleneck:
// ~34 ds_read_b128 per 32 MFMA meant ~60-70% LDS-pipe occupancy at CU level).
// Each wave now owns 32 q-rows (two register-resident A-fragment sets), so
// every Ks/Vs ds_read_b128 feeds TWO MFMAs. BQ=128 per block, K/V staging and
// swizzle unchanged, Ps swizzled (no pad) to fit 80 KB LDS = 2 blocks/CU.
// Grid pair-balances heavy+light q-tiles per CU. Math bit-identical.

#define D 2048
#define NH 16
#define DH 128
#define BB 2
#define LL 2048
#define BHD (BB*NH)      // 32
#define MROWS (BB*LL)    // 4096
#define KDIM D

typedef __attribute__((ext_vector_type(8))) short short8;
typedef __attribute__((ext_vector_type(4))) float floatx4;

// fp32 -> bf16, round-to-nearest-even
__device__ __forceinline__ unsigned short f2bf(float f) {
    unsigned u = __float_as_uint(f);
    unsigned r = u + 0x7FFFu + ((u >> 16) & 1u);
    return (unsigned short)(r >> 16);
}
__device__ __forceinline__ float bf2f(unsigned short u) {
    return __uint_as_float(((unsigned)u) << 16);
}

// async global->LDS DMA, 16 B/lane; LDS dest is wave-uniform base + lane*16
__device__ __forceinline__ void async16(const void* g, void* lds) {
    __builtin_amdgcn_global_load_lds(
        (const __attribute__((address_space(1))) unsigned int*)g,
        (__attribute__((address_space(3))) unsigned int*)lds, 16, 0, 0);
}

// DPP lane-move within 16-lane rows (VALU-speed, no LDS pipe).
// ctrl: 0xB1 = quad_perm xor1, 0x4E = quad_perm xor2,
//       0x124 = row_ror:4, 0x128 = row_ror:8
template<int CTRL>
__device__ __forceinline__ float dpp_movf(float x) {
    return __int_as_float(__builtin_amdgcn_update_dpp(
        0, __float_as_int(x), CTRL, 0xF, 0xF, true));
}
__device__ __forceinline__ float row_max16(float x) {
    x = fmaxf(x, dpp_movf<0xB1>(x));
    x = fmaxf(x, dpp_movf<0x4E>(x));
    x = fmaxf(x, dpp_movf<0x124>(x));
    x = fmaxf(x, dpp_movf<0x128>(x));
    return x;
}
__device__ __forceinline__ float row_sum16(float x) {
    x += dpp_movf<0xB1>(x);
    x += dpp_movf<0x4E>(x);
    x += dpp_movf<0x124>(x);
    x += dpp_movf<0x128>(x);
    return x;
}

// ---------------------------------------------------------------------------
// elementwise fp32 -> bf16 cast, float4-vectorized
// ---------------------------------------------------------------------------
__global__ __launch_bounds__(256)
void cast_bf16_kernel_v2(const float* __restrict__ in,
                         unsigned short* __restrict__ out, int n4)
{
    int i = blockIdx.x * 256 + threadIdx.x;
    if (i < n4) {
        float4 v = ((const float4*)in)[i];
        ushort4 o;
        o.x = f2bf(v.x); o.y = f2bf(v.y); o.z = f2bf(v.z); o.w = f2bf(v.w);
        ((ushort4*)out)[i] = o;
    }
}

// ---------------------------------------------------------------------------
// W (K x N fp32 row-major) -> Wt (N x K bf16 row-major), 32x32 LDS tiles
// ---------------------------------------------------------------------------
__global__ __launch_bounds__(256)
void transpose_cast_kernel_v2(const float* __restrict__ W,
                              unsigned short* __restrict__ Wt, int K, int N)
{
    __shared__ float tile[32][33];
    const int tx = threadIdx.x & 31, ty = threadIdx.x >> 5;  // ty in 0..7
    const int n0 = blockIdx.x * 32, k0 = blockIdx.y * 32;
#pragma unroll
    for (int r = 0; r < 4; r++)
        tile[ty + 8 * r][tx] = W[(size_t)(k0 + ty + 8 * r) * N + n0 + tx];
    __syncthreads();
#pragma unroll
    for (int r = 0; r < 4; r++)
        Wt[(size_t)(n0 + ty + 8 * r) * K + k0 + tx] = f2bf(tile[tx][ty + 8 * r]);
}

// ---------------------------------------------------------------------------
// V (bh, l, dh) -> Vt (bh, dh, l), bf16, 32x32 LDS tiles (+2B pad row)
// ---------------------------------------------------------------------------
__global__ __launch_bounds__(256)
void transpose_v_kernel_v2(const unsigned short* __restrict__ Vb,
                           unsigned short* __restrict__ VtG)
{
    __shared__ unsigned short tile[32][34];
    const int tx = threadIdx.x & 31, ty = threadIdx.x >> 5;
    const int l0 = blockIdx.x * 32, d0 = blockIdx.y * 32;
    const int bh = blockIdx.z;
    const unsigned short* src = Vb + (size_t)bh * LL * DH;
    unsigned short* dst = VtG + (size_t)bh * DH * LL;
#pragma unroll
    for (int r = 0; r < 4; r++)
        tile[ty + 8 * r][tx] = src[(size_t)(l0 + ty + 8 * r) * DH + d0 + tx];
    __syncthreads();
#pragma unroll
    for (int r = 0; r < 4; r++)
        dst[(size_t)(d0 + ty + 8 * r) * LL + l0 + tx] = tile[tx][ty + 8 * r];
}

// ---------------------------------------------------------------------------
// bf16 MFMA GEMM, m97 structure: C(MxN) = A(MxK) * Bt(NxK)^T.
// 128x128 block tile, BK=32, 4 waves each owning a 64x64 quadrant.
// MODE 0: fp32 store to C. MODE 1: bf16 scatter to Q/K/V in (B,H,L,Dh).
// ---------------------------------------------------------------------------
template<int N, int MODE>
__global__ __launch_bounds__(256)
void mfma_gemm_v2(const unsigned short* __restrict__ A,
                  const unsigned short* __restrict__ Bt,
                  float* __restrict__ C, unsigned short* __restrict__ Qo,
                  unsigned short* __restrict__ Ko, unsigned short* __restrict__ Vo)
{
    __shared__ unsigned short As[128 * 32];   // [m][k] contiguous (DMA order)
    __shared__ unsigned short Bs[128 * 32];   // [n][k] contiguous
    const int t = threadIdx.x;
    const int w = t >> 6, lane = t & 63;
    const int lrow = lane & 15, quad = lane >> 4;
    const int m0 = blockIdx.y * 128, n0 = blockIdx.x * 128;
    const int wm = (w >> 1) * 64, wn = (w & 1) * 64;

    floatx4 acc[4][4];
#pragma unroll
    for (int i = 0; i < 4; i++)
#pragma unroll
        for (int j = 0; j < 4; j++) acc[i][j] = (floatx4){0.f, 0.f, 0.f, 0.f};

    const int srow = 32 * w + (lane >> 2);
    const int sseg = (lane & 3) * 8;

    for (int k0 = 0; k0 < KDIM; k0 += 32) {
        __syncthreads();
        async16(&A [(size_t)(m0 + srow)      * KDIM + k0 + sseg], &As[(32 * w)      * 32]);
        async16(&A [(size_t)(m0 + srow + 16) * KDIM + k0 + sseg], &As[(32 * w + 16) * 32]);
        async16(&Bt[(size_t)(n0 + srow)      * KDIM + k0 + sseg], &Bs[(32 * w)      * 32]);
        async16(&Bt[(size_t)(n0 + srow + 16) * KDIM + k0 + sseg], &Bs[(32 * w + 16) * 32]);
        __syncthreads();

        short8 a[4], b[4];
#pragma unroll
        for (int i = 0; i < 4; i++)
            a[i] = *(const short8*)&As[(wm + i * 16 + lrow) * 32 + quad * 8];
#pragma unroll
        for (int j = 0; j < 4; j++)
            b[j] = *(const short8*)&Bs[(wn + j * 16 + lrow) * 32 + quad * 8];
#pragma unroll
        for (int i = 0; i < 4; i++)
#pragma unroll
            for (int j = 0; j < 4; j++)
                acc[i][j] = __builtin_amdgcn_mfma_f32_16x16x32_bf16(a[i], b[j], acc[i][j], 0, 0, 0);
    }

    // C/D fragment layout: col = lane&15, row = quad*4 + reg (m89-verified)
    if (MODE == 0) {
#pragma unroll
        for (int i = 0; i < 4; i++)
#pragma unroll
            for (int j = 0; j < 4; j++) {
                int col = n0 + wn + j * 16 + lrow;
#pragma unroll
                for (int r = 0; r < 4; r++) {
                    int m = m0 + wm + i * 16 + quad * 4 + r;
                    C[(size_t)m * N + col] = acc[i][j][r];
                }
            }
    } else {
        const int s = n0 >> 11;              // qkv slot, uniform per block
        const int h = (n0 & 2047) >> 7;
        unsigned short* dst = (s == 0) ? Qo : (s == 1) ? Ko : Vo;
#pragma unroll
        for (int i = 0; i < 4; i++)
#pragma unroll
            for (int j = 0; j < 4; j++) {
                int dh = wn + j * 16 + lrow;
#pragma unroll
                for (int r = 0; r < 4; r++) {
                    int m = m0 + wm + i * 16 + quad * 4 + r;
                    int b = m >> 11, l = m & 2047;
                    dst[(((size_t)b * NH + h) * LL + l) * DH + dh] = f2bf(acc[i][j][r]);
                }
            }
    }
}

// ---------------------------------------------------------------------------
// RoPE + L2-normalize, in place on bf16 Q/K (fp32 internal); Q *= s_qk.
// One 128-thread block per (bh, l).
// ---------------------------------------------------------------------------
__global__ __launch_bounds__(128)
void rope_norm_kernel_v2(unsigned short* __restrict__ Q,
                         unsigned short* __restrict__ K,
                         const float* __restrict__ s_qk_ptr)
{
    const int l  = blockIdx.x;
    const int bh = blockIdx.y;
    const int d  = threadIdx.x;
    __shared__ float sh[128];

    const size_t base = ((size_t)bh * LL + l) * DH + d;
    float qv = bf2f(Q[base]);
    float kv = bf2f(K[base]);

    const int i = d & 63;
    // inv_freq = 10000^(-i/64); ln(10000)/64 = 0.14391156831
    float ang = (float)l * expf(-0.14391157f * (float)i);
    float c = cosf(ang), s = sinf(ang);

    sh[d] = qv; __syncthreads();
    float qrot = (d < 64) ? -sh[d + 64] : sh[d - 64];
    float qr = fmaf(qv, c, qrot * s);
    __syncthreads();

    sh[d] = kv; __syncthreads();
    float krot = (d < 64) ? -sh[d + 64] : sh[d - 64];
    float kr = fmaf(kv, c, krot * s);
    __syncthreads();

    sh[d] = qr * qr; __syncthreads();
    for (int st = 64; st > 0; st >>= 1) {
        if (d < st) sh[d] += sh[d + st];
        __syncthreads();
    }
    float qn = sqrtf(sh[0]);
    __syncthreads();

    sh[d] = kr * kr; __syncthreads();
    for (int st = 64; st > 0; st >>= 1) {
        if (d < st) sh[d] += sh[d + st];
        __syncthreads();
    }
    float kn = sqrtf(sh[0]);

    float sqk = s_qk_ptr[0];
    Q[base] = f2bf(qr / fmaxf(qn, 1e-12f) * sqk);
    K[base] = f2bf(kr / fmaxf(kn, 1e-12f));
}

// ---------------------------------------------------------------------------
// bf16 MFMA flash attention, causal. Round 11 structure:
//   BQ=128 per block, 4 waves x 32 q-rows each; BK=64.
//   Each wave holds TWO 16-row Q A-fragment sets in registers, so every
//   Ks/Vs ds_read_b128 feeds two MFMAs (halves LDS-pipe demand per FLOP).
//   Ps is [4][32][64] with the same 16B-slot XOR swizzle as Ks/Vs (no pad).
//   LDS = 32+32+16 = 80 KB -> exactly 2 blocks/CU.
//   Grid (32 bh, 16 y): qt = y<8 ? 15-y : y-8 pairs heavy+light blocks
//   per CU (uniform 36 kv-tiles/CU) to kill the drain tail.
// ---------------------------------------------------------------------------
#define ABQ 128
#define ABK 64
__global__ __launch_bounds__(256, 2)
void attn_mfma_kernel_v5(const unsigned short* __restrict__ Q,
                         const unsigned short* __restrict__ K,
                         const unsigned short* __restrict__ Vt,
                         unsigned short* __restrict__ AOb)
{
    __shared__ __align__(16) unsigned short Ks[2][ABK * DH];   // 32 KB
    __shared__ __align__(16) unsigned short Vs[2][DH * ABK];   // 32 KB
    __shared__ __align__(16) unsigned short Ps[4][32][64];     // 16 KB swizzled

    const int t = threadIdx.x;
    const int w = t >> 6, lane = t & 63;
    const int lrow = lane & 15, quad = lane >> 4;
    const int bh = blockIdx.x;
    const int y  = blockIdx.y;
    const int qt = (y < 8) ? (15 - y) : (y - 8);   // pair-balanced mapping
    const int q0 = qt * ABQ;
    const int qw = q0 + w * 32;                    // wave's first q-row

    const unsigned short* Qb = Q  + (size_t)bh * LL * DH;
    const unsigned short* Kb = K  + (size_t)bh * LL * DH;
    const unsigned short* Vg = Vt + (size_t)bh * DH * LL;

    // Q A-fragments, two 16-row halves, all in registers:
    // row = qw + 16h + lrow, k = kk*32 + quad*8 + e
    short8 aq[2][4];
#pragma unroll
    for (int h = 0; h < 2; h++)
#pragma unroll
        for (int kk = 0; kk < 4; kk++)
            aq[h][kk] = *(const short8*)&Qb[(size_t)(qw + 16 * h + lrow) * DH
                                            + kk * 32 + quad * 8];

    floatx4 oacc[2][8];
#pragma unroll
    for (int h = 0; h < 2; h++)
#pragma unroll
        for (int dt = 0; dt < 8; dt++) oacc[h][dt] = (floatx4){0.f, 0.f, 0.f, 0.f};
    float mrow[2][4], lsum[2][4];
#pragma unroll
    for (int h = 0; h < 2; h++)
#pragma unroll
        for (int r = 0; r < 4; r++) { mrow[h][r] = -1e30f; lsum[h][r] = 0.f; }

    // stage one K/V tile into buffer `buf`; LDS dest linear, global source
    // column slot inverse-swizzled so that swizzled reads see row-major data
    auto STAGE = [&](int tile, int buf) {
        const int k0s = tile * ABK;
#pragma unroll
        for (int c = 0; c < 4; c++) {
            int row = 16 * w + 4 * c;
            int r   = row + (lane >> 4);
            int col = (lane & 15) ^ (r & 7);
            async16(&Kb[(size_t)(k0s + r) * DH + col * 8], &Ks[buf][row * DH]);
        }
#pragma unroll
        for (int c = 0; c < 4; c++) {
            int row = 32 * w + 8 * c;
            int r   = row + (lane >> 3);
            int col = (lane & 7) ^ (r & 7);
            async16(&Vg[(size_t)r * LL + k0s + col * 8], &Vs[buf][row * ABK]);
        }
    };

    const int ntiles = 2 * qt + 2;
    STAGE(0, 0);
    __syncthreads();

    int cur = 0;
    for (int tile = 0; tile < ntiles; tile++) {
        const int k0 = tile * ABK;
        if (tile + 1 < ntiles) STAGE(tile + 1, cur ^ 1);

        // S = Q K^T; sacc[h][j]: rows qw+16h+quad*4+r, keys k0+j*16+lrow
        floatx4 sacc[2][4];
#pragma unroll
        for (int h = 0; h < 2; h++)
#pragma unroll
            for (int j = 0; j < 4; j++) sacc[h][j] = (floatx4){0.f, 0.f, 0.f, 0.f};
        __builtin_amdgcn_s_setprio(1);
#pragma unroll
        for (int kk = 0; kk < 4; kk++) {
#pragma unroll
            for (int j = 0; j < 4; j++) {
                int slot = (kk * 4 + quad) ^ (lrow & 7);
                short8 bk = *(const short8*)&Ks[cur][(j * 16 + lrow) * DH + slot * 8];
                sacc[0][j] = __builtin_amdgcn_mfma_f32_16x16x32_bf16(aq[0][kk], bk, sacc[0][j], 0, 0, 0);
                sacc[1][j] = __builtin_amdgcn_mfma_f32_16x16x32_bf16(aq[1][kk], bk, sacc[1][j], 0, 0, 0);
            }
        }
        __builtin_amdgcn_s_setprio(0);

        // causal mask (per 16-row half; fires near the diagonal only)
#pragma unroll
        for (int h = 0; h < 2; h++) {
            if (k0 + ABK - 1 > qw + 16 * h) {
#pragma unroll
                for (int j = 0; j < 4; j++) {
                    int key = k0 + j * 16 + lrow;
#pragma unroll
                    for (int r = 0; r < 4; r++) {
                        int q = qw + 16 * h + quad * 4 + r;
                        if (key > q) sacc[h][j][r] = -1e30f;
                    }
                }
            }
        }

        // online softmax per half; DPP cross-lane reductions (VALU pipe)
#pragma unroll
        for (int h = 0; h < 2; h++) {
            float alpha[4];
#pragma unroll
            for (int r = 0; r < 4; r++) {
                float mt = fmaxf(fmaxf(sacc[h][0][r], sacc[h][1][r]),
                                 fmaxf(sacc[h][2][r], sacc[h][3][r]));
                mt = row_max16(mt);
                float mn = fmaxf(mrow[h][r], mt);
                alpha[r] = __expf(mrow[h][r] - mn);
                mrow[h][r] = mn;
            }
            // P = exp(S - m): bf16 into swizzled per-wave LDS; row sums
#pragma unroll
            for (int r = 0; r < 4; r++) {
                int rowp = 16 * h + quad * 4 + r;
                float rs = 0.f;
#pragma unroll
                for (int j = 0; j < 4; j++) {
                    float p = __expf(sacc[h][j][r] - mrow[h][r]);
                    rs += p;
                    // col = j*16+lrow; 16B-slot swizzle: slot ^= rowp&7
                    int slot = (2 * j + (lrow >> 3)) ^ (rowp & 7);
                    Ps[w][rowp][slot * 8 + (lrow & 7)] = f2bf(p);
                }
                rs = row_sum16(rs);
                lsum[h][r] = lsum[h][r] * alpha[r] + rs;
            }
            // O = O*alpha
#pragma unroll
            for (int dt = 0; dt < 8; dt++)
#pragma unroll
                for (int r = 0; r < 4; r++) oacc[h][dt][r] *= alpha[r];
        }

        // O += P @ V ; each bv read feeds both halves
        __builtin_amdgcn_s_setprio(1);
#pragma unroll
        for (int kk2 = 0; kk2 < 2; kk2++) {
            int pslot = (kk2 * 4 + quad) ^ (lrow & 7);
            short8 pa0 = *(const short8*)&Ps[w][lrow][pslot * 8];
            short8 pa1 = *(const short8*)&Ps[w][16 + lrow][pslot * 8];
#pragma unroll
            for (int dt = 0; dt < 8; dt++) {
                int slot = (kk2 * 4 + quad) ^ (lrow & 7);
                short8 bv = *(const short8*)&Vs[cur][(dt * 16 + lrow) * ABK + slot * 8];
                oacc[0][dt] = __builtin_amdgcn_mfma_f32_16x16x32_bf16(pa0, bv, oacc[0][dt], 0, 0, 0);
                oacc[1][dt] = __builtin_amdgcn_mfma_f32_16x16x32_bf16(pa1, bv, oacc[1][dt], 0, 0, 0);
            }
        }
        __builtin_amdgcn_s_setprio(0);

        __syncthreads();   // drains prefetch vmcnt + guards buffer reuse
        cur ^= 1;
    }

    // epilogue: divide by row sum, store bf16 to (B, L, D)
    const int b = bh >> 4, hd = bh & 15;
#pragma unroll
    for (int h = 0; h < 2; h++)
#pragma unroll
        for (int r = 0; r < 4; r++) {
            float inv = 1.f / lsum[h][r];
            int q = qw + 16 * h + quad * 4 + r;
            size_t base = ((size_t)b * LL + q) * D + hd * DH;
#pragma unroll
            for (int dt = 0; dt < 8; dt++)
                AOb[base + dt * 16 + lrow] = f2bf(oacc[h][dt][r] * inv);
        }
}

// ---------------------------------------------------------------------------
extern "C" void kernel_launch(void* const* d_in, const int* in_sizes, int n_in,
                              void* d_out, int out_size, void* d_ws, size_t ws_size,
                              hipStream_t stream)
{
    const float* x     = (const float*)d_in[0];
    const float* w_qkv = (const float*)d_in[1];
    const float* w_out = (const float*)d_in[2];
    const float* s_qk  = (const float*)d_in[3];
    float* out = (float*)d_out;

    const size_t SZ = (size_t)BB * NH * LL * DH;   // 8388608 elements
    unsigned short* u = (unsigned short*)d_ws;
    unsigned short* xb    = u;                               // x bf16 -> later AO bf16
    unsigned short* wqkvT = xb    + (size_t)MROWS * KDIM;    // 6144 x 2048
    unsigned short* woutT = wqkvT + (size_t)(3 * D) * KDIM;  // 2048 x 2048
    unsigned short* Qb    = woutT + (size_t)D * KDIM;
    unsigned short* Kb    = Qb + SZ;
    unsigned short* Vb    = Kb + SZ;
    unsigned short* VtG   = Vb + SZ;

    // 1) x -> bf16
    cast_bf16_kernel_v2<<<(MROWS * KDIM / 4 + 255) / 256, 256, 0, stream>>>(
        x, xb, MROWS * KDIM / 4);
    // 2) w_qkv -> (3D x K) bf16
    transpose_cast_kernel_v2<<<dim3(3 * D / 32, KDIM / 32), 256, 0, stream>>>(
        w_qkv, wqkvT, KDIM, 3 * D);
    // 3) QKV projection, bf16 scatter into (B,H,L,Dh)
    mfma_gemm_v2<3 * D, 1><<<dim3(3 * D / 128, MROWS / 128), 256, 0, stream>>>(
        xb, wqkvT, nullptr, Qb, Kb, Vb);
    // 4) RoPE + normalize in place (+ s_qk into Q)
    rope_norm_kernel_v2<<<dim3(LL, BHD), 128, 0, stream>>>(Qb, Kb, s_qk);
    // 5) V -> V^T (bh, dh, l)
    transpose_v_kernel_v2<<<dim3(LL / 32, DH / 32, BHD), 256, 0, stream>>>(Vb, VtG);
    // 6) flash attention -> AO bf16 (B,L,D), reusing xb
    attn_mfma_kernel_v5<<<dim3(BHD, LL / ABQ), 256, 0, stream>>>(Qb, Kb, VtG, xb);
    // 7) w_out -> bf16
    transpose_cast_kernel_v2<<<dim3(D / 32, D / 32), 256, 0, stream>>>(
        w_out, woutT, D, D);
    // 8) output projection
    mfma_gemm_v2<D, 0><<<dim3(D / 128, MROWS / 128), 256, 0, stream>>>(
        xb, woutT, out, nullptr, nullptr, nullptr);
}